// Round 1
// baseline (512.499 us; speedup 1.0000x reference)
//
#include <hip/hip_runtime.h>
#include <hip/hip_bf16.h>

// Problem constants (compile-time; reference shapes are fixed)
#define VOCAB 50000
#define D     300
#define B_    64
#define LC    32
#define T_    256
#define LT    64
#define NSEL  5

#define CROW  320           // padded floats per claim row (swizzled image), mult of 32
#define CIMG  (LC * CROW)   // 10240 floats per batch image
#define K4N   75            // 300 / 4 float4 steps
#define TPB   256
#define TCH   4             // t's per block in score kernel

// ws layout (floats):
//   wsC   : [B_][CIMG]   swizzled claim-embedding images   (655360 f)
//   wsScr : [B_][T_]     target scores                     (16384 f)
//   wsIdx : [B_][NSEL]   top-5 indices (ints)

__device__ __forceinline__ float dot4acc(float4 c, float4 e, float a) {
    a = fmaf(c.x, e.x, a); a = fmaf(c.y, e.y, a);
    a = fmaf(c.z, e.z, a); a = fmaf(c.w, e.w, a);
    return a;
}

// ---------------- K1: gather claim embeddings into swizzled ws image ----------
__global__ void k_gather_claim(const int* __restrict__ claim,
                               const float* __restrict__ emb,
                               float* __restrict__ wsC) {
    int row = blockIdx.x;            // 0..B_*LC-1
    int b = row >> 5, c = row & 31;
    int tok = claim[row];
    const float* src = emb + (size_t)tok * D;
    float* dst = wsC + (size_t)b * CIMG + c * CROW;
    int key = c >> 2;                // 0..7 — must match read-side cg
    for (int k = threadIdx.x; k < CROW; k += 64) {
        float v = (k < D) ? src[k] : 0.0f;
        int k4 = k >> 2, kr = k & 3;
        dst[((k4 ^ key) << 2) + kr] = v;   // XOR-swizzled float4 slots
    }
}

// Shared main loop: computes S[32][64] for one (b,t), thread layout:
// cg = tid&7 (c-group of 4 rows), lp = tid>>3 (pair of l columns)
__device__ __forceinline__ void compute_tile(const float* sC,
                                             const float* __restrict__ emb,
                                             const int* __restrict__ trow,
                                             int tid, float* sS) {
    int cg = tid & 7;
    int l0 = (tid >> 3) * 2;
    int tok0 = trow[l0];
    int tok1 = trow[l0 + 1];
    const float4* e0p = (const float4*)(emb + (size_t)tok0 * D);
    const float4* e1p = (const float4*)(emb + (size_t)tok1 * D);
    const float4* cp0 = (const float4*)(sC + (cg * 4 + 0) * CROW);
    const float4* cp1 = (const float4*)(sC + (cg * 4 + 1) * CROW);
    const float4* cp2 = (const float4*)(sC + (cg * 4 + 2) * CROW);
    const float4* cp3 = (const float4*)(sC + (cg * 4 + 3) * CROW);

    float a00 = 0.f, a01 = 0.f, a10 = 0.f, a11 = 0.f;
    float a20 = 0.f, a21 = 0.f, a30 = 0.f, a31 = 0.f;

#pragma unroll 3
    for (int k4 = 0; k4 < K4N; ++k4) {
        float4 e0 = e0p[k4];
        float4 e1 = e1p[k4];
        int ks = k4 ^ cg;                 // undo swizzle; conflict-free b128
        float4 c0 = cp0[ks], c1 = cp1[ks], c2 = cp2[ks], c3 = cp3[ks];
        a00 = dot4acc(c0, e0, a00); a01 = dot4acc(c0, e1, a01);
        a10 = dot4acc(c1, e0, a10); a11 = dot4acc(c1, e1, a11);
        a20 = dot4acc(c2, e0, a20); a21 = dot4acc(c2, e1, a21);
        a30 = dot4acc(c3, e0, a30); a31 = dot4acc(c3, e1, a31);
    }
    int c0i = cg * 4;
    sS[(c0i + 0) * 66 + l0] = a00; sS[(c0i + 0) * 66 + l0 + 1] = a01;
    sS[(c0i + 1) * 66 + l0] = a10; sS[(c0i + 1) * 66 + l0 + 1] = a11;
    sS[(c0i + 2) * 66 + l0] = a20; sS[(c0i + 2) * 66 + l0 + 1] = a21;
    sS[(c0i + 3) * 66 + l0] = a30; sS[(c0i + 3) * 66 + l0 + 1] = a31;
}

// ---------------- K2: target scores --------------------------------------
__global__ __launch_bounds__(TPB) void k_scores(const int* __restrict__ targets,
                                                const float* __restrict__ emb,
                                                const float* __restrict__ wsC,
                                                float* __restrict__ wsScr) {
    __shared__ __align__(16) float sC[CIMG];
    __shared__ float sS[LC * 66];
    __shared__ float sM[LC], sD[LC];
    int b = blockIdx.y;
    int tbase = blockIdx.x * TCH;
    int tid = threadIdx.x;

    {   // stage swizzled claim image (verbatim copy)
        const float4* src = (const float4*)(wsC + (size_t)b * CIMG);
        float4* dst = (float4*)sC;
        for (int i = tid; i < CIMG / 4; i += TPB) dst[i] = src[i];
    }
    __syncthreads();

    for (int tt = 0; tt < TCH; ++tt) {
        int t = tbase + tt;
        const int* trow = targets + ((size_t)b * T_ + t) * LT;
        compute_tile(sC, emb, trow, tid, sS);
        __syncthreads();

        if (tid < LC) {                 // per-claim-row max & softmax denom
            const float* r = sS + tid * 66;
            float m = -1e30f;
            for (int l = 0; l < LT; ++l) m = fmaxf(m, r[l]);
            float s = 0.f;
            for (int l = 0; l < LT; ++l) s += __expf(r[l] - m);
            sM[tid] = m; sD[tid] = 1.0f / s;
        }
        __syncthreads();

        if (tid < LT) {                 // score_l = max_c softmax; sum over l
            int l = tid;
            float best = 0.f;
            for (int c = 0; c < LC; ++c)
                best = fmaxf(best, __expf(sS[c * 66 + l] - sM[c]) * sD[c]);
            for (int off = 32; off > 0; off >>= 1)
                best += __shfl_down(best, off);
            if (tid == 0) wsScr[b * T_ + t] = best;
        }
        __syncthreads();                // protect sS before next t overwrites
    }
}

// ---------------- K3: top-5 per batch (descending, lowest-index ties) -----
__global__ void k_topn(const float* __restrict__ wsScr, int* __restrict__ wsIdx) {
    int b = blockIdx.x;
    int tid = threadIdx.x;              // 64 threads = 1 wave
    float v[4];
    for (int i = 0; i < 4; ++i) v[i] = wsScr[b * T_ + tid + 64 * i];
    for (int r = 0; r < NSEL; ++r) {
        float bv = v[0]; int bi = tid;
        for (int i = 1; i < 4; ++i) {
            int idx = tid + 64 * i;
            if (v[i] > bv) { bv = v[i]; bi = idx; }
        }
        for (int off = 32; off > 0; off >>= 1) {
            float ov = __shfl_down(bv, off);
            int   oi = __shfl_down(bi, off);
            if (ov > bv || (ov == bv && oi < bi)) { bv = ov; bi = oi; }
        }
        bi = __shfl(bi, 0);
        if (tid == 0) wsIdx[b * NSEL + r] = bi;
        if ((bi & 63) == tid) v[bi >> 6] = -1e30f;   // remove winner
    }
}

// ---------------- K4: recompute selected tiles, L2-normalize rows ---------
__global__ __launch_bounds__(TPB) void k_output(const int* __restrict__ targets,
                                                const float* __restrict__ emb,
                                                const float* __restrict__ wsC,
                                                const int* __restrict__ wsIdx,
                                                float* __restrict__ out) {
    __shared__ __align__(16) float sC[CIMG];
    __shared__ float sS[LC * 66];
    __shared__ float sR[LC];
    int b = blockIdx.y, j = blockIdx.x, tid = threadIdx.x;

    {
        const float4* src = (const float4*)(wsC + (size_t)b * CIMG);
        float4* dst = (float4*)sC;
        for (int i = tid; i < CIMG / 4; i += TPB) dst[i] = src[i];
    }
    __syncthreads();

    int t = wsIdx[b * NSEL + j];
    const int* trow = targets + ((size_t)b * T_ + t) * LT;
    compute_tile(sC, emb, trow, tid, sS);
    __syncthreads();

    if (tid < LC) {                      // 1/||row||_2 over LT axis
        const float* r = sS + tid * 66;
        float ss = 0.f;
        for (int l = 0; l < LT; ++l) ss = fmaf(r[l], r[l], ss);
        sR[tid] = 1.0f / sqrtf(ss);
    }
    __syncthreads();

    float* orow = out + (size_t)(b * NSEL + j) * (LC * LT);
    for (int i = tid; i < LC * LT; i += TPB) {
        int c = i >> 6, l = i & 63;
        orow[i] = sS[c * 66 + l] * sR[c];
    }
}

extern "C" void kernel_launch(void* const* d_in, const int* in_sizes, int n_in,
                              void* d_out, int out_size, void* d_ws, size_t ws_size,
                              hipStream_t stream) {
    const int*   claim   = (const int*)d_in[0];
    const int*   targets = (const int*)d_in[1];
    const float* emb     = (const float*)d_in[2];
    // d_in[3] is n (=5), compile-time NSEL

    float* wsC   = (float*)d_ws;
    float* wsScr = wsC + (size_t)B_ * CIMG;
    int*   wsIdx = (int*)(wsScr + B_ * T_);
    float* out   = (float*)d_out;

    k_gather_claim<<<dim3(B_ * LC), dim3(64), 0, stream>>>(claim, emb, wsC);
    k_scores<<<dim3(T_ / TCH, B_), dim3(TPB), 0, stream>>>(targets, emb, wsC, wsScr);
    k_topn<<<dim3(B_), dim3(64), 0, stream>>>(wsScr, wsIdx);
    k_output<<<dim3(NSEL, B_), dim3(TPB), 0, stream>>>(targets, emb, wsC, wsIdx, out);
}